// Round 19
// baseline (196.551 us; speedup 1.0000x reference)
//
#include <hip/hip_runtime.h>
#include <hip/hip_bf16.h>
#include <cstdint>

// ---------- types ----------
typedef __bf16 bf16x8 __attribute__((ext_vector_type(8)));
typedef __bf16 bf16x4 __attribute__((ext_vector_type(4)));
typedef __bf16 bf16x2 __attribute__((ext_vector_type(2)));
typedef float  f32x4  __attribute__((ext_vector_type(4)));
typedef __attribute__((address_space(3))) __bf16 lds_bf16;
typedef __attribute__((address_space(1))) const __bf16 gl_bf16;

// ---------- merged fp32 -> bf16 convert (exact-sized 1-D grid) ----------
// wq/wk segments are written ROW-PERMUTED: within each 128-row head,
// original row d -> ((d&63)<<1) + (d>>6)  (pair-interleave: RoPE partner
// d^64 becomes the adjacent row). Inverse applied in the GEMM epilogue.
__global__ void cvt_all(const float* __restrict__ s0, __bf16* __restrict__ d0,
                        const float* __restrict__ s1, __bf16* __restrict__ d1,
                        const float* __restrict__ s2, __bf16* __restrict__ d2,
                        const float* __restrict__ s3, __bf16* __restrict__ d3,
                        const float* __restrict__ s4, __bf16* __restrict__ d4) {
    const int blk = blockIdx.x;
    const float* s; __bf16* d; int base; bool perm = false;
    if (blk < 8192)       { s = s0; d = d0; base = blk; }
    else if (blk < 12288) { s = s1; d = d1; base = blk - 8192;  perm = true; }
    else if (blk < 12800) { s = s2; d = d2; base = blk - 12288; perm = true; }
    else if (blk < 13312) { s = s3; d = d3; base = blk - 12800; }
    else                  { s = s4; d = d4; base = blk - 13312; }
    const int i = (base * 256 + threadIdx.x) * 4;
    float4 v = *reinterpret_cast<const float4*>(s + i);
    bf16x4 o;
    o.x = (__bf16)v.x; o.y = (__bf16)v.y; o.z = (__bf16)v.z; o.w = (__bf16)v.w;
    int iout = i;
    if (perm) {
        const int row = base >> 1;                 // 1024 elems = half row of 2048
        const int h = row >> 7, dd = row & 127;
        const int pr = (h << 7) + ((dd & 63) << 1) + (dd >> 6);
        iout = pr * 2048 + (base & 1) * 1024 + threadIdx.x * 4;
    }
    *reinterpret_cast<bf16x4*>(d + iout) = o;
}

// ---------- concat bq|bk|bv (Q/K parts pair-interleave-permuted) ----------
__global__ void concat_bias(const float* __restrict__ bq, const float* __restrict__ bk,
                            const float* __restrict__ bv, float* __restrict__ dst) {
    int t = blockIdx.x * blockDim.x + threadIdx.x;
    if (t < 2048) {
        const int h = t >> 7, d = t & 127;
        dst[(h << 7) + ((d & 63) << 1) + (d >> 6)] = bq[t];
    } else if (t < 2304) {
        const int u = t - 2048, kvh = u >> 7, d = u & 127;
        dst[2048 + (kvh << 7) + ((d & 63) << 1) + (d >> 6)] = bk[u];
    } else if (t < 2560) {
        dst[t] = bv[t - 2304];
    }
}

// ---------- stage one 128x64 half-tile: 2 global_load_lds per thread ----------
__device__ __forceinline__ void stage_half(const __bf16* __restrict__ gbase, int K, int k0,
                                           lds_bf16* lbase, int tid) {
    const int cc = (tid & 7) ^ ((tid >> 3) & 7);
    const __bf16* s0 = gbase + (size_t)(tid >> 3) * K + k0 + cc * 8;
    __builtin_amdgcn_global_load_lds((gl_bf16*)s0, lbase + (tid >> 6) * 512, 16, 0, 0);
    const __bf16* s1 = gbase + (size_t)(64 + (tid >> 3)) * K + k0 + cc * 8;
    __builtin_amdgcn_global_load_lds((gl_bf16*)s1, lbase + 4096 + (tid >> 6) * 512, 16, 0, 0);
}

// ---------- stage a 320x64 B-tile: 5 stripes of 64 rows ----------
__device__ __forceinline__ void stage_B5(const __bf16* __restrict__ gbase, int K, int k0,
                                         lds_bf16* lbase, int tid) {
    const int cc = (tid & 7) ^ ((tid >> 3) & 7);
    #pragma unroll
    for (int s = 0; s < 5; ++s) {
        const __bf16* src = gbase + (size_t)(s * 64 + (tid >> 3)) * K + k0 + cc * 8;
        __builtin_amdgcn_global_load_lds((gl_bf16*)src, lbase + s * 4096 + (tid >> 6) * 512, 16, 0, 0);
    }
}

// ---------- out-proj GEMM (unchanged): 256x128 tile, grid 256 ----------
__global__ __launch_bounds__(512)
void gemm_out(const __bf16* __restrict__ A, const __bf16* __restrict__ B,
              float* __restrict__ C) {
    const int K = 2048, NT = 32;
    __shared__ __align__(16) char smem[98304];

    const int tid  = threadIdx.x;
    const int wave = tid >> 6, lane = tid & 63, lg = lane >> 4, ll = lane & 15;
    const int wr = wave >> 2, wc = wave & 3;

    const int orig = blockIdx.x;
    const int wg   = (orig & 7) * 32 + (orig >> 3);
    const int bm = wg >> 4, bn = wg & 15;

    const __bf16* Atile = A + (size_t)(bm * 256) * K;
    const __bf16* Btile = B + (size_t)(bn * 128) * K;

    lds_bf16* AsL = (lds_bf16*)smem;
    lds_bf16* BsL = (lds_bf16*)(smem + 65536);

    f32x4 acc[8][2];
    #pragma unroll
    for (int m = 0; m < 8; ++m)
        #pragma unroll
        for (int n = 0; n < 2; ++n)
            acc[m][n] = f32x4{0.f, 0.f, 0.f, 0.f};

    stage_half(Atile,                 K, 0, AsL,        tid);
    stage_half(Atile + (size_t)128*K, K, 0, AsL + 8192, tid);
    stage_half(Btile,                 K, 0, BsL,        tid);

    const char* smB = (const char*)smem;
    for (int t = 0; t < NT; ++t) {
        const int c   = t & 1;
        const int bfn = c ^ 1;
        const int k0n = ((t + 1 < NT) ? t + 1 : t) * 64;
        const char* AbB = smB + c * 32768 + wr * 16384;
        const char* BbB = smB + 65536 + c * 16384;
        bf16x8 af[8][2], bq[2][2];

        stage_half(Atile,                 K, k0n, AsL + bfn * 8192 * 2,        tid);
        stage_half(Atile + (size_t)128*K, K, k0n, AsL + bfn * 8192 * 2 + 8192, tid);
        asm volatile("s_waitcnt vmcnt(4)" ::: "memory");
        __builtin_amdgcn_s_barrier();
        asm volatile("" ::: "memory");
        #pragma unroll
        for (int kk = 0; kk < 2; ++kk) {
            #pragma unroll
            for (int mm = 0; mm < 8; ++mm)
                af[mm][kk] = *reinterpret_cast<const bf16x8*>(
                    AbB + (mm * 16 + ll) * 128 + (((kk * 4 + lg) ^ (ll & 7)) << 4));
            #pragma unroll
            for (int nn = 0; nn < 2; ++nn)
                bq[nn][kk] = *reinterpret_cast<const bf16x8*>(
                    BbB + (wc * 32 + nn * 16 + ll) * 128 + (((kk * 4 + lg) ^ (ll & 7)) << 4));
        }
        __builtin_amdgcn_s_setprio(1);
        #pragma unroll
        for (int kk = 0; kk < 2; ++kk)
            #pragma unroll
            for (int mm = 0; mm < 4; ++mm)
                #pragma unroll
                for (int nn = 0; nn < 2; ++nn)
                    acc[mm][nn] = __builtin_amdgcn_mfma_f32_16x16x32_bf16(af[mm][kk], bq[nn][kk], acc[mm][nn], 0, 0, 0);
        __builtin_amdgcn_s_setprio(0);
        asm volatile("" ::: "memory");
        __builtin_amdgcn_s_barrier();
        asm volatile("" ::: "memory");

        stage_half(Btile, K, k0n, BsL + bfn * 8192, tid);
        __builtin_amdgcn_s_setprio(1);
        #pragma unroll
        for (int kk = 0; kk < 2; ++kk)
            #pragma unroll
            for (int mm = 0; mm < 4; ++mm)
                #pragma unroll
                for (int nn = 0; nn < 2; ++nn)
                    acc[4 + mm][nn] = __builtin_amdgcn_mfma_f32_16x16x32_bf16(af[4 + mm][kk], bq[nn][kk], acc[4 + mm][nn], 0, 0, 0);
        __builtin_amdgcn_s_setprio(0);
        asm volatile("" ::: "memory");
        __builtin_amdgcn_s_barrier();
        asm volatile("" ::: "memory");
    }

    asm volatile("s_waitcnt vmcnt(0)" ::: "memory");

    #pragma unroll
    for (int m = 0; m < 8; ++m)
        #pragma unroll
        for (int n = 0; n < 2; ++n) {
            const int col = bn * 128 + wc * 32 + n * 16 + ll;
            #pragma unroll
            for (int r = 0; r < 4; ++r) {
                const int rowg = bm * 256 + wr * 128 + m * 16 + lg * 4 + r;
                C[(size_t)rowg * 2048 + col] = acc[m][n][r];
            }
        }
}

// ---------- QKV GEMM 128x320, BK=64, grid 256 (full fill), fused bias+RoPE ----------
__global__ __launch_bounds__(512)
void gemm_qkv_rope(const __bf16* __restrict__ A, const __bf16* __restrict__ B,
                   const float* __restrict__ bias, const float* __restrict__ cosb,
                   const float* __restrict__ sinb, __bf16* __restrict__ qT,
                   __bf16* __restrict__ kT, __bf16* __restrict__ vT) {
    const int K = 2048, NT = 32;
    __shared__ __align__(16) char smem[114688];   // A: 2x16KB [0,32K); B: 2x40KB [32K,112K)

    const int tid  = threadIdx.x;
    const int wave = tid >> 6, lane = tid & 63, lg = lane >> 4, ll = lane & 15;
    const int wr = wave >> 2, wc = wave & 3;       // 2M x 4N; per-wave 64 x 80

    const int orig = blockIdx.x;                   // 256 wg, %8 == 0
    const int wg   = (orig & 7) * 32 + (orig >> 3);
    const int bm = wg >> 3, bn = wg & 7;           // 32 x 8

    const __bf16* Atile = A + (size_t)(bm * 128) * K;
    const __bf16* Btile = B + (size_t)(bn * 320) * K;

    lds_bf16* AsL = (lds_bf16*)smem;               // per buf 8192 elems
    lds_bf16* BsL = (lds_bf16*)(smem + 32768);     // per buf 20480 elems

    f32x4 acc[4][5];
    #pragma unroll
    for (int m = 0; m < 4; ++m)
        #pragma unroll
        for (int n = 0; n < 5; ++n)
            acc[m][n] = f32x4{0.f, 0.f, 0.f, 0.f};

    // prologue: tile 0 -> buf 0
    stage_half(Atile, K, 0, AsL, tid);
    stage_B5 (Btile, K, 0, BsL, tid);
    asm volatile("s_waitcnt vmcnt(0)" ::: "memory");
    __syncthreads();

    const char* smB = (const char*)smem;
    for (int t = 0; t < NT; ++t) {
        const int c   = t & 1;
        const int bfn = c ^ 1;
        const int k0n = ((t + 1 < NT) ? t + 1 : t) * 64;   // clamp keeps counts uniform

        // issue next tile's 7 loads
        stage_half(Atile, K, k0n, AsL + bfn * 8192,  tid);
        stage_B5 (Btile, K, k0n, BsL + bfn * 20480, tid);
        asm volatile("s_waitcnt vmcnt(7)" ::: "memory");   // retire THIS tile's 7
        __builtin_amdgcn_s_barrier();
        asm volatile("" ::: "memory");

        const char* AbB = smB + c * 16384 + wr * 8192;
        const char* BbB = smB + 32768 + c * 40960;
        bf16x8 af[4][2], bq[5][2];
        #pragma unroll
        for (int kk = 0; kk < 2; ++kk) {
            #pragma unroll
            for (int mm = 0; mm < 4; ++mm)
                af[mm][kk] = *reinterpret_cast<const bf16x8*>(
                    AbB + (mm * 16 + ll) * 128 + (((kk * 4 + lg) ^ (ll & 7)) << 4));
            #pragma unroll
            for (int nn = 0; nn < 5; ++nn)
                bq[nn][kk] = *reinterpret_cast<const bf16x8*>(
                    BbB + (wc * 80 + nn * 16 + ll) * 128 + (((kk * 4 + lg) ^ (ll & 7)) << 4));
        }
        __builtin_amdgcn_s_setprio(1);
        #pragma unroll
        for (int kk = 0; kk < 2; ++kk)
            #pragma unroll
            for (int mm = 0; mm < 4; ++mm)
                #pragma unroll
                for (int nn = 0; nn < 5; ++nn)
                    acc[mm][nn] = __builtin_amdgcn_mfma_f32_16x16x32_bf16(af[mm][kk], bq[nn][kk], acc[mm][nn], 0, 0, 0);
        __builtin_amdgcn_s_setprio(0);
        asm volatile("" ::: "memory");
        __builtin_amdgcn_s_barrier();
        asm volatile("" ::: "memory");
    }

    asm volatile("s_waitcnt vmcnt(0)" ::: "memory");   // drain clamped tail prefetch

    // ---- epilogue: per-section (uniform per 16-lane group) ----
    const float qscale = 0.08838834764831845f * 1.4426950408889634f;
    #pragma unroll
    for (int n = 0; n < 5; ++n) {
        const int scol = bn * 320 + wc * 80 + n * 16;   // 16-aligned section base
        const int gcol = scol + ll;
        if (scol >= 2304) {
            // V: bias only, transposed store (b, kv, d, l)
            const int kvh = (gcol - 2304) >> 7, d = (gcol - 2304) & 127;
            const float bv = bias[gcol];
            #pragma unroll
            for (int m = 0; m < 4; ++m) {
                const int rbase = bm * 128 + wr * 64 + m * 16 + lg * 4;
                const int b = rbase >> 11, l0 = rbase & 2047;
                bf16x4 o4;
                #pragma unroll
                for (int r = 0; r < 4; ++r) o4[r] = (__bf16)(acc[m][n][r] + bv);
                *reinterpret_cast<bf16x4*>(&vT[((size_t)(b * 2 + kvh) * 128 + d) * 2048 + l0]) = o4;
            }
        } else {
            const bool isQ = (scol < 2048);
            const float qsc = isQ ? qscale : 1.0f;
            const int p = gcol & 127;                       // pair-interleaved index
            const int d_out = (p >> 1) + ((p & 1) << 6);    // original d
            const float sgn = (p & 1) ? 1.f : -1.f;
            const float bv = bias[gcol];
            #pragma unroll
            for (int m = 0; m < 4; ++m) {
                #pragma unroll
                for (int r = 0; r < 4; ++r) {
                    const float self = acc[m][n][r] + bv;
                    const float part = __shfl_xor(self, 1);
                    const int rowg = bm * 128 + wr * 64 + m * 16 + lg * 4 + r;
                    const int b = rowg >> 11, l = rowg & 2047;
                    const float cc = cosb[l * 128 + d_out], ss = sinb[l * 128 + d_out];
                    const float val = (self * cc + sgn * part * ss) * qsc;
                    if (isQ) {
                        const int h = gcol >> 7;
                        qT[(((size_t)(b * 16 + h)) * 2048 + l) * 128 + d_out] = (__bf16)val;
                    } else {
                        const int kvh = (gcol - 2048) >> 7;
                        kT[(((size_t)(b * 2 + kvh)) * 2048 + l) * 128 + d_out] = (__bf16)val;
                    }
                }
            }
        }
    }
}

// ---------- attn softmax helper (scores s[4] -> probs; online state m, sr) ----------
__device__ __forceinline__ void attn_softmax(f32x4* s, f32x4* o, float& mrow, float& srow) {
    float tmax = s[0][0];
    #pragma unroll
    for (int n = 0; n < 4; ++n)
        #pragma unroll
        for (int r = 0; r < 4; ++r) tmax = fmaxf(tmax, s[n][r]);
    tmax = fmaxf(tmax, __shfl_xor(tmax, 16));
    tmax = fmaxf(tmax, __shfl_xor(tmax, 32));
    if (__any(tmax > mrow + 8.f)) {        // T13 defer-max
        const float mnew = fmaxf(mrow, tmax);
        const float scl = __builtin_amdgcn_exp2f(mrow - mnew);
        mrow = mnew;
        srow *= scl;
        #pragma unroll
        for (int nd = 0; nd < 8; ++nd)
            #pragma unroll
            for (int r = 0; r < 4; ++r) o[nd][r] *= scl;
    }
    float rs = 0.f;
    #pragma unroll
    for (int n = 0; n < 4; ++n)
        #pragma unroll
        for (int r = 0; r < 4; ++r) {
            const float p = __builtin_amdgcn_exp2f(s[n][r] - mrow);
            s[n][r] = p;
            rs += p;
        }
    rs += __shfl_xor(rs, 16);
    rs += __shfl_xor(rs, 32);
    srow += rs;
}

// P-store: packed bf16x4 (b64), row = ll, logical chunk 2n+(lg>>1), half lg&1
__device__ __forceinline__ void attn_pstore(const f32x4* s, char* P, int lg, int ll) {
    #pragma unroll
    for (int n = 0; n < 4; ++n) {
        bf16x4 pk;
        #pragma unroll
        for (int r = 0; r < 4; ++r) pk[r] = (__bf16)s[n][r];
        const int chunk = 2 * n + (lg >> 1);
        *reinterpret_cast<bf16x4*>(
            P + ll * 128 + ((chunk ^ (ll & 7)) << 4) + (lg & 1) * 8) = pk;
    }
}

// ---------- causal GQA flash attention: 128 q-rows/block, 32 q-rows/wave ----------
// grid 512 = 16 (qp) x 32 (hb), balanced remap (pair-sum 36 steps). Each wave
// owns two 16-row sub-groups A/B; one shared kf read feeds both QK MFMAs, one
// shared vf read feeds both PV MFMAs -> K/V LDS traffic per q-row HALVED.
// LDS: K 16K | V 16K | P 16K (2KB per wave per sub) = 48KB -> 3 blocks/CU.
__global__ __launch_bounds__(256)
void attn_kernel(const __bf16* __restrict__ qT, const __bf16* __restrict__ kT,
                 const __bf16* __restrict__ vT, __bf16* __restrict__ attnb) {
    const int bx = blockIdx.x;             // 512 blocks
    const int g5 = bx >> 5;
    const int qp = (g5 < 8) ? g5 : 23 - g5;   // bijective on [0,15]
    const int hb = bx & 31;
    const int h = hb >> 1, b = hb & 1;
    const int kv = h >> 3;
    const int tid = threadIdx.x, wave = tid >> 6, lane = tid & 63, lg = lane >> 4, ll = lane & 15;
    const int qlocA = wave * 32 + ll;      // q-row within the 128-row block
    const int qlocB = qlocA + 16;

    __shared__ __align__(16) char smem[49152];   // K 16K | V 16K | P 16K
    lds_bf16* ldsE = (lds_bf16*)smem;

    const __bf16* kbase = kT + (size_t)((b * 2 + kv) * 2048) * 128;
    const __bf16* vbase = vT + (size_t)((b * 2 + kv) * 128) * 2048;

    bf16x8 qfA[4], qfB[4];
    {
        const __bf16* q0 = qT + ((size_t)((b * 16 + h) * 2048) + qp * 128 + wave * 32 + ll) * 128;
        #pragma unroll
        for (int kk = 0; kk < 4; ++kk) {
            qfA[kk] = *reinterpret_cast<const bf16x8*>(q0 + kk * 32 + lg * 8);
            qfB[kk] = *reinterpret_cast<const bf16x8*>(q0 + 16 * 128 + kk * 32 + lg * 8);
        }
    }

    f32x4 oA[8], oB[8];
    #pragma unroll
    for (int nd = 0; nd < 8; ++nd) { oA[nd] = f32x4{0.f,0.f,0.f,0.f}; oB[nd] = f32x4{0.f,0.f,0.f,0.f}; }
    float mA = -3e38f, srA = 0.f, mB = -3e38f, srB = 0.f;

    const int ntiles = 2 * qp + 2;

    #define STAGE_KV(j0)                                                                   \
        do {                                                                               \
            lds_bf16* kl = ldsE;                                                           \
            lds_bf16* vl = ldsE + 8192;                                                    \
            _Pragma("unroll")                                                              \
            for (int i = 0; i < 4; ++i) {                                                  \
                const int li = i * 256 + tid;                                              \
                const int key = li >> 4, c = li & 15;                                      \
                const __bf16* src = kbase + (size_t)((j0) + key) * 128 + ((c ^ (key & 7)) * 8); \
                __builtin_amdgcn_global_load_lds((gl_bf16*)src, kl + i * 2048 + wave * 512, 16, 0, 0); \
            }                                                                              \
            _Pragma("unroll")                                                              \
            for (int i = 0; i < 4; ++i) {                                                  \
                const int li = i * 256 + tid;                                              \
                const int dd = li >> 3, cv = li & 7;                                       \
                const __bf16* src = vbase + (size_t)dd * 2048 + (j0) + ((cv ^ (dd & 7)) * 8); \
                __builtin_amdgcn_global_load_lds((gl_bf16*)src, vl + i * 2048 + wave * 512, 16, 0, 0); \
            }                                                                              \
        } while (0)

    // prologue: stage tile 0
    STAGE_KV(0);
    asm volatile("s_waitcnt vmcnt(0)" ::: "memory");
    __syncthreads();

    const char* KlB = smem;
    const char* VlB = smem + 16384;
    char* PlA = smem + 32768 + wave * 4096;
    char* PlB_ = PlA + 2048;

    for (int t = 0; t < ntiles; ++t) {
        // ---- QK^T for both sub-groups; shared kf reads
        f32x4 sA[4], sB[4];
        #pragma unroll
        for (int n = 0; n < 4; ++n) { sA[n] = f32x4{0.f,0.f,0.f,0.f}; sB[n] = f32x4{0.f,0.f,0.f,0.f}; }
        __builtin_amdgcn_s_setprio(1);
        #pragma unroll
        for (int kk = 0; kk < 4; ++kk)
            #pragma unroll
            for (int n = 0; n < 4; ++n) {
                const int row = n * 16 + ll;
                bf16x8 kf = *reinterpret_cast<const bf16x8*>(
                    KlB + row * 256 + (((kk * 4 + lg) ^ (ll & 7)) << 4));
                sA[n] = __builtin_amdgcn_mfma_f32_16x16x32_bf16(kf, qfA[kk], sA[n], 0, 0, 0);
                sB[n] = __builtin_amdgcn_mfma_f32_16x16x32_bf16(kf, qfB[kk], sB[n], 0, 0, 0);
            }
        __builtin_amdgcn_s_setprio(0);

        // ---- diagonal mask (last two tiles only)
        const int rel = t * 64 - qp * 128;
        if (rel >= 0) {
            #pragma unroll
            for (int n = 0; n < 4; ++n)
                #pragma unroll
                for (int r = 0; r < 4; ++r) {
                    const int key = rel + n * 16 + lg * 4 + r;
                    if (key > qlocA) sA[n][r] = -3e38f;
                    if (key > qlocB) sB[n][r] = -3e38f;
                }
        }

        // ---- softmax + P stores (per sub)
        attn_softmax(sA, oA, mA, srA);
        attn_pstore(sA, PlA, lg, ll);
        attn_softmax(sB, oB, mB, srB);
        attn_pstore(sB, PlB_, lg, ll);

        // ---- PV for both subs; shared vf reads
        __builtin_amdgcn_s_setprio(1);
        #pragma unroll
        for (int kk = 0; kk < 2; ++kk) {
            bf16x8 pfA = *reinterpret_cast<const bf16x8*>(
                PlA + ll * 128 + (((kk * 4 + lg) ^ (ll & 7)) << 4));
            bf16x8 pfB = *reinterpret_cast<const bf16x8*>(
                PlB_ + ll * 128 + (((kk * 4 + lg) ^ (ll & 7)) << 4));
            #pragma unroll
            for (int nd = 0; nd < 8; ++nd) {
                const int row = nd * 16 + ll;
                bf16x8 vf = *reinterpret_cast<const bf16x8*>(
                    VlB + row * 128 + (((kk * 4 + lg) ^ (ll & 7)) << 4));
                oA[nd] = __builtin_amdgcn_mfma_f32_16x16x32_bf16(vf, pfA, oA[nd], 0, 0, 0);
                oB[nd] = __builtin_amdgcn_mfma_f32_16x16x32_bf16(vf, pfB, oB[nd], 0, 0, 0);
            }
        }
        __builtin_amdgcn_s_setprio(0);

        if (t + 1 < ntiles) {
            asm volatile("" ::: "memory");
            __builtin_amdgcn_s_barrier();   // all waves done reading tile t
            asm volatile("" ::: "memory");
            STAGE_KV((t + 1) * 64);
            asm volatile("s_waitcnt vmcnt(0)" ::: "memory");
            __builtin_amdgcn_s_barrier();   // tile t+1 visible
            asm volatile("" ::: "memory");
        }
    }

    // epilogue
    const float invA = __builtin_amdgcn_rcpf(srA);
    const float invB = __builtin_amdgcn_rcpf(srB);
    const int qrowA = qp * 128 + wave * 32 + ll;
    const int qrowB = qrowA + 16;
    #pragma unroll
    for (int nd = 0; nd < 8; ++nd) {
        bf16x4 a4, b4;
        #pragma unroll
        for (int r = 0; r < 4; ++r) {
            a4[r] = (__bf16)(oA[nd][r] * invA);
            b4[r] = (__bf16)(oB[nd][r] * invB);
        }
        const size_t cb = h * 128 + nd * 16 + lg * 4;
        *reinterpret_cast<bf16x4*>(&attnb[((size_t)(b * 2048) + qrowA) * 2048 + cb]) = a4;
        *reinterpret_cast<bf16x4*>(&attnb[((size_t)(b * 2048) + qrowB) * 2048 + cb]) = b4;
    }
    #undef STAGE_KV
}

// ---------- host launch ----------
extern "C" void kernel_launch(void* const* d_in, const int* in_sizes, int n_in,
                              void* d_out, int out_size, void* d_ws, size_t ws_size,
                              hipStream_t stream) {
    const float* x    = (const float*)d_in[0];
    const float* cosb = (const float*)d_in[1];
    const float* sinb = (const float*)d_in[2];
    const float* wq   = (const float*)d_in[3];
    const float* bq   = (const float*)d_in[4];
    const float* wk   = (const float*)d_in[5];
    const float* bk   = (const float*)d_in[6];
    const float* wv   = (const float*)d_in[7];
    const float* bv   = (const float*)d_in[8];
    const float* wo   = (const float*)d_in[9];
    float* out = (float*)d_out;

    char* ws = (char*)d_ws;
    __bf16* xb    = (__bf16*)(ws);                         // 16,777,216  (later reused as attnb)
    __bf16* wb    = (__bf16*)(ws + 16777216);              // 10,485,760  (wq|wk|wv rows, 2560x2048)
    __bf16* wob   = (__bf16*)(ws + 27262976);              //  8,388,608
    float*  biasc = (float*) (ws + 35651584);              //     16,384 (2560 used)
    __bf16* qTp   = (__bf16*)(ws + 77611008);              // 16,777,216
    __bf16* kTp   = (__bf16*)(ws + 94388224);              //  2,097,152
    __bf16* vTp   = (__bf16*)(ws + 96485376);              //  2,097,152

    // 1) convert all fp32 inputs to bf16 (wq/wk pair-interleave-permuted)
    cvt_all<<<17408, 256, 0, stream>>>(
        x,  xb,
        wq, wb,
        wk, wb + 4194304,
        wv, wb + 4718592,
        wo, wob);
    concat_bias<<<10, 256, 0, stream>>>(bq, bk, bv, biasc);

    // 2) fused QKV GEMM + bias + RoPE + layout  [256 wg = full fill, 512 thr, BK=64]
    gemm_qkv_rope<<<256, 512, 0, stream>>>(xb, wb, biasc, cosb, sinb, qTp, kTp, vTp);

    // 3) flash attention -> attnb  [512 blocks, 128 q-rows/block, 48KB LDS]
    attn_kernel<<<512, 256, 0, stream>>>(qTp, kTp, vTp, xb);

    // 4) output GEMM: 256x128 tiles, grid 256 (perfect fill), pipelined
    gemm_out<<<256, 512, 0, stream>>>(xb, wob, out);
}

// Round 20
// 178.206 us; speedup vs baseline: 1.1029x; 1.1029x over previous
//
#include <hip/hip_runtime.h>
#include <hip/hip_bf16.h>
#include <cstdint>

// ---------- types ----------
typedef __bf16 bf16x8 __attribute__((ext_vector_type(8)));
typedef __bf16 bf16x4 __attribute__((ext_vector_type(4)));
typedef __bf16 bf16x2 __attribute__((ext_vector_type(2)));
typedef float  f32x4  __attribute__((ext_vector_type(4)));
typedef __attribute__((address_space(3))) __bf16 lds_bf16;
typedef __attribute__((address_space(1))) const __bf16 gl_bf16;

// ---------- merged fp32 -> bf16 convert (exact-sized 1-D grid) ----------
// wq/wk segments are written ROW-PERMUTED: within each 128-row head,
// original row d -> ((d&63)<<1) + (d>>6)  (pair-interleave: RoPE partner
// d^64 becomes the adjacent row). Inverse applied in the GEMM epilogue.
__global__ void cvt_all(const float* __restrict__ s0, __bf16* __restrict__ d0,
                        const float* __restrict__ s1, __bf16* __restrict__ d1,
                        const float* __restrict__ s2, __bf16* __restrict__ d2,
                        const float* __restrict__ s3, __bf16* __restrict__ d3,
                        const float* __restrict__ s4, __bf16* __restrict__ d4) {
    const int blk = blockIdx.x;
    const float* s; __bf16* d; int base; bool perm = false;
    if (blk < 8192)       { s = s0; d = d0; base = blk; }
    else if (blk < 12288) { s = s1; d = d1; base = blk - 8192;  perm = true; }
    else if (blk < 12800) { s = s2; d = d2; base = blk - 12288; perm = true; }
    else if (blk < 13312) { s = s3; d = d3; base = blk - 12800; }
    else                  { s = s4; d = d4; base = blk - 13312; }
    const int i = (base * 256 + threadIdx.x) * 4;
    float4 v = *reinterpret_cast<const float4*>(s + i);
    bf16x4 o;
    o.x = (__bf16)v.x; o.y = (__bf16)v.y; o.z = (__bf16)v.z; o.w = (__bf16)v.w;
    int iout = i;
    if (perm) {
        const int row = base >> 1;                 // 1024 elems = half row of 2048
        const int h = row >> 7, dd = row & 127;
        const int pr = (h << 7) + ((dd & 63) << 1) + (dd >> 6);
        iout = pr * 2048 + (base & 1) * 1024 + threadIdx.x * 4;
    }
    *reinterpret_cast<bf16x4*>(d + iout) = o;
}

// ---------- concat bq|bk|bv (Q/K parts pair-interleave-permuted) ----------
__global__ void concat_bias(const float* __restrict__ bq, const float* __restrict__ bk,
                            const float* __restrict__ bv, float* __restrict__ dst) {
    int t = blockIdx.x * blockDim.x + threadIdx.x;
    if (t < 2048) {
        const int h = t >> 7, d = t & 127;
        dst[(h << 7) + ((d & 63) << 1) + (d >> 6)] = bq[t];
    } else if (t < 2304) {
        const int u = t - 2048, kvh = u >> 7, d = u & 127;
        dst[2048 + (kvh << 7) + ((d & 63) << 1) + (d >> 6)] = bk[u];
    } else if (t < 2560) {
        dst[t] = bv[t - 2304];
    }
}

// ---------- stage one 128x64 half-tile: 2 global_load_lds per thread ----------
__device__ __forceinline__ void stage_half(const __bf16* __restrict__ gbase, int K, int k0,
                                           lds_bf16* lbase, int tid) {
    const int cc = (tid & 7) ^ ((tid >> 3) & 7);
    const __bf16* s0 = gbase + (size_t)(tid >> 3) * K + k0 + cc * 8;
    __builtin_amdgcn_global_load_lds((gl_bf16*)s0, lbase + (tid >> 6) * 512, 16, 0, 0);
    const __bf16* s1 = gbase + (size_t)(64 + (tid >> 3)) * K + k0 + cc * 8;
    __builtin_amdgcn_global_load_lds((gl_bf16*)s1, lbase + 4096 + (tid >> 6) * 512, 16, 0, 0);
}

// ---------- stage a 320x64 B-tile: 5 stripes of 64 rows ----------
__device__ __forceinline__ void stage_B5(const __bf16* __restrict__ gbase, int K, int k0,
                                         lds_bf16* lbase, int tid) {
    const int cc = (tid & 7) ^ ((tid >> 3) & 7);
    #pragma unroll
    for (int s = 0; s < 5; ++s) {
        const __bf16* src = gbase + (size_t)(s * 64 + (tid >> 3)) * K + k0 + cc * 8;
        __builtin_amdgcn_global_load_lds((gl_bf16*)src, lbase + s * 4096 + (tid >> 6) * 512, 16, 0, 0);
    }
}

// ---------- out-proj GEMM: 256x128 tile, grid 256 (perfect fill) ----------
__global__ __launch_bounds__(512)
void gemm_out(const __bf16* __restrict__ A, const __bf16* __restrict__ B,
              float* __restrict__ C) {
    const int K = 2048, NT = 32;
    __shared__ __align__(16) char smem[98304];

    const int tid  = threadIdx.x;
    const int wave = tid >> 6, lane = tid & 63, lg = lane >> 4, ll = lane & 15;
    const int wr = wave >> 2, wc = wave & 3;

    const int orig = blockIdx.x;
    const int wg   = (orig & 7) * 32 + (orig >> 3);
    const int bm = wg >> 4, bn = wg & 15;

    const __bf16* Atile = A + (size_t)(bm * 256) * K;
    const __bf16* Btile = B + (size_t)(bn * 128) * K;

    lds_bf16* AsL = (lds_bf16*)smem;
    lds_bf16* BsL = (lds_bf16*)(smem + 65536);

    f32x4 acc[8][2];
    #pragma unroll
    for (int m = 0; m < 8; ++m)
        #pragma unroll
        for (int n = 0; n < 2; ++n)
            acc[m][n] = f32x4{0.f, 0.f, 0.f, 0.f};

    stage_half(Atile,                 K, 0, AsL,        tid);
    stage_half(Atile + (size_t)128*K, K, 0, AsL + 8192, tid);
    stage_half(Btile,                 K, 0, BsL,        tid);

    const char* smB = (const char*)smem;
    for (int t = 0; t < NT; ++t) {
        const int c   = t & 1;
        const int bfn = c ^ 1;
        const int k0n = ((t + 1 < NT) ? t + 1 : t) * 64;
        const char* AbB = smB + c * 32768 + wr * 16384;
        const char* BbB = smB + 65536 + c * 16384;
        bf16x8 af[8][2], bq[2][2];

        stage_half(Atile,                 K, k0n, AsL + bfn * 8192 * 2,        tid);
        stage_half(Atile + (size_t)128*K, K, k0n, AsL + bfn * 8192 * 2 + 8192, tid);
        asm volatile("s_waitcnt vmcnt(4)" ::: "memory");
        __builtin_amdgcn_s_barrier();
        asm volatile("" ::: "memory");
        #pragma unroll
        for (int kk = 0; kk < 2; ++kk) {
            #pragma unroll
            for (int mm = 0; mm < 8; ++mm)
                af[mm][kk] = *reinterpret_cast<const bf16x8*>(
                    AbB + (mm * 16 + ll) * 128 + (((kk * 4 + lg) ^ (ll & 7)) << 4));
            #pragma unroll
            for (int nn = 0; nn < 2; ++nn)
                bq[nn][kk] = *reinterpret_cast<const bf16x8*>(
                    BbB + (wc * 32 + nn * 16 + ll) * 128 + (((kk * 4 + lg) ^ (ll & 7)) << 4));
        }
        __builtin_amdgcn_s_setprio(1);
        #pragma unroll
        for (int kk = 0; kk < 2; ++kk)
            #pragma unroll
            for (int mm = 0; mm < 4; ++mm)
                #pragma unroll
                for (int nn = 0; nn < 2; ++nn)
                    acc[mm][nn] = __builtin_amdgcn_mfma_f32_16x16x32_bf16(af[mm][kk], bq[nn][kk], acc[mm][nn], 0, 0, 0);
        __builtin_amdgcn_s_setprio(0);
        asm volatile("" ::: "memory");
        __builtin_amdgcn_s_barrier();
        asm volatile("" ::: "memory");

        stage_half(Btile, K, k0n, BsL + bfn * 8192, tid);
        __builtin_amdgcn_s_setprio(1);
        #pragma unroll
        for (int kk = 0; kk < 2; ++kk)
            #pragma unroll
            for (int mm = 0; mm < 4; ++mm)
                #pragma unroll
                for (int nn = 0; nn < 2; ++nn)
                    acc[4 + mm][nn] = __builtin_amdgcn_mfma_f32_16x16x32_bf16(af[4 + mm][kk], bq[nn][kk], acc[4 + mm][nn], 0, 0, 0);
        __builtin_amdgcn_s_setprio(0);
        asm volatile("" ::: "memory");
        __builtin_amdgcn_s_barrier();
        asm volatile("" ::: "memory");
    }

    asm volatile("s_waitcnt vmcnt(0)" ::: "memory");

    #pragma unroll
    for (int m = 0; m < 8; ++m)
        #pragma unroll
        for (int n = 0; n < 2; ++n) {
            const int col = bn * 128 + wc * 32 + n * 16 + ll;
            #pragma unroll
            for (int r = 0; r < 4; ++r) {
                const int rowg = bm * 256 + wr * 128 + m * 16 + lg * 4 + r;
                C[(size_t)rowg * 2048 + col] = acc[m][n][r];
            }
        }
}

// ---------- QKV GEMM 128x320, BK=64, grid 256 (full fill), fused bias+RoPE ----------
__global__ __launch_bounds__(512)
void gemm_qkv_rope(const __bf16* __restrict__ A, const __bf16* __restrict__ B,
                   const float* __restrict__ bias, const float* __restrict__ cosb,
                   const float* __restrict__ sinb, __bf16* __restrict__ qT,
                   __bf16* __restrict__ kT, __bf16* __restrict__ vT) {
    const int K = 2048, NT = 32;
    __shared__ __align__(16) char smem[114688];   // A: 2x16KB [0,32K); B: 2x40KB [32K,112K)

    const int tid  = threadIdx.x;
    const int wave = tid >> 6, lane = tid & 63, lg = lane >> 4, ll = lane & 15;
    const int wr = wave >> 2, wc = wave & 3;       // 2M x 4N; per-wave 64 x 80

    const int orig = blockIdx.x;                   // 256 wg, %8 == 0
    const int wg   = (orig & 7) * 32 + (orig >> 3);
    const int bm = wg >> 3, bn = wg & 7;           // 32 x 8

    const __bf16* Atile = A + (size_t)(bm * 128) * K;
    const __bf16* Btile = B + (size_t)(bn * 320) * K;

    lds_bf16* AsL = (lds_bf16*)smem;               // per buf 8192 elems
    lds_bf16* BsL = (lds_bf16*)(smem + 32768);     // per buf 20480 elems

    f32x4 acc[4][5];
    #pragma unroll
    for (int m = 0; m < 4; ++m)
        #pragma unroll
        for (int n = 0; n < 5; ++n)
            acc[m][n] = f32x4{0.f, 0.f, 0.f, 0.f};

    // prologue: tile 0 -> buf 0
    stage_half(Atile, K, 0, AsL, tid);
    stage_B5 (Btile, K, 0, BsL, tid);
    asm volatile("s_waitcnt vmcnt(0)" ::: "memory");
    __syncthreads();

    const char* smB = (const char*)smem;
    for (int t = 0; t < NT; ++t) {
        const int c   = t & 1;
        const int bfn = c ^ 1;
        const int k0n = ((t + 1 < NT) ? t + 1 : t) * 64;   // clamp keeps counts uniform

        // issue next tile's 7 loads
        stage_half(Atile, K, k0n, AsL + bfn * 8192,  tid);
        stage_B5 (Btile, K, k0n, BsL + bfn * 20480, tid);
        asm volatile("s_waitcnt vmcnt(7)" ::: "memory");   // retire THIS tile's 7
        __builtin_amdgcn_s_barrier();
        asm volatile("" ::: "memory");

        const char* AbB = smB + c * 16384 + wr * 8192;
        const char* BbB = smB + 32768 + c * 40960;
        bf16x8 af[4][2], bq[5][2];
        #pragma unroll
        for (int kk = 0; kk < 2; ++kk) {
            #pragma unroll
            for (int mm = 0; mm < 4; ++mm)
                af[mm][kk] = *reinterpret_cast<const bf16x8*>(
                    AbB + (mm * 16 + ll) * 128 + (((kk * 4 + lg) ^ (ll & 7)) << 4));
            #pragma unroll
            for (int nn = 0; nn < 5; ++nn)
                bq[nn][kk] = *reinterpret_cast<const bf16x8*>(
                    BbB + (wc * 80 + nn * 16 + ll) * 128 + (((kk * 4 + lg) ^ (ll & 7)) << 4));
        }
        __builtin_amdgcn_s_setprio(1);
        #pragma unroll
        for (int kk = 0; kk < 2; ++kk)
            #pragma unroll
            for (int mm = 0; mm < 4; ++mm)
                #pragma unroll
                for (int nn = 0; nn < 5; ++nn)
                    acc[mm][nn] = __builtin_amdgcn_mfma_f32_16x16x32_bf16(af[mm][kk], bq[nn][kk], acc[mm][nn], 0, 0, 0);
        __builtin_amdgcn_s_setprio(0);
        asm volatile("" ::: "memory");
        __builtin_amdgcn_s_barrier();
        asm volatile("" ::: "memory");
    }

    asm volatile("s_waitcnt vmcnt(0)" ::: "memory");   // drain clamped tail prefetch

    // ---- epilogue: per-section (uniform per 16-lane group) ----
    const float qscale = 0.08838834764831845f * 1.4426950408889634f;
    #pragma unroll
    for (int n = 0; n < 5; ++n) {
        const int scol = bn * 320 + wc * 80 + n * 16;   // 16-aligned section base
        const int gcol = scol + ll;
        if (scol >= 2304) {
            // V: bias only, transposed store (b, kv, d, l)
            const int kvh = (gcol - 2304) >> 7, d = (gcol - 2304) & 127;
            const float bv = bias[gcol];
            #pragma unroll
            for (int m = 0; m < 4; ++m) {
                const int rbase = bm * 128 + wr * 64 + m * 16 + lg * 4;
                const int b = rbase >> 11, l0 = rbase & 2047;
                bf16x4 o4;
                #pragma unroll
                for (int r = 0; r < 4; ++r) o4[r] = (__bf16)(acc[m][n][r] + bv);
                *reinterpret_cast<bf16x4*>(&vT[((size_t)(b * 2 + kvh) * 128 + d) * 2048 + l0]) = o4;
            }
        } else {
            const bool isQ = (scol < 2048);
            const float qsc = isQ ? qscale : 1.0f;
            const int p = gcol & 127;                       // pair-interleaved index
            const int d_out = (p >> 1) + ((p & 1) << 6);    // original d
            const float sgn = (p & 1) ? 1.f : -1.f;
            const float bv = bias[gcol];
            #pragma unroll
            for (int m = 0; m < 4; ++m) {
                #pragma unroll
                for (int r = 0; r < 4; ++r) {
                    const float self = acc[m][n][r] + bv;
                    const float part = __shfl_xor(self, 1);
                    const int rowg = bm * 128 + wr * 64 + m * 16 + lg * 4 + r;
                    const int b = rowg >> 11, l = rowg & 2047;
                    const float cc = cosb[l * 128 + d_out], ss = sinb[l * 128 + d_out];
                    const float val = (self * cc + sgn * part * ss) * qsc;
                    if (isQ) {
                        const int h = gcol >> 7;
                        qT[(((size_t)(b * 16 + h)) * 2048 + l) * 128 + d_out] = (__bf16)val;
                    } else {
                        const int kvh = (gcol - 2048) >> 7;
                        kT[(((size_t)(b * 2 + kvh)) * 2048 + l) * 128 + d_out] = (__bf16)val;
                    }
                }
            }
        }
    }
}

// ---------- attn: one Q-group step with wave-uniform defer-max (T13) ----------
__device__ __forceinline__ void attn_step(const char* KlB, const char* VlB, char* PlB,
                                          const bf16x8* qf, f32x4* o, float& mrow, float& srow,
                                          bool diag, int lg, int ll, int qloc) {
    f32x4 s[4];
    #pragma unroll
    for (int n = 0; n < 4; ++n) s[n] = f32x4{0.f, 0.f, 0.f, 0.f};
    __builtin_amdgcn_s_setprio(1);
    #pragma unroll
    for (int kk = 0; kk < 4; ++kk)
        #pragma unroll
        for (int n = 0; n < 4; ++n) {
            const int row = n * 16 + ll;
            bf16x8 kf = *reinterpret_cast<const bf16x8*>(
                KlB + row * 256 + (((kk * 4 + lg) ^ (ll & 7)) << 4));
            s[n] = __builtin_amdgcn_mfma_f32_16x16x32_bf16(kf, qf[kk], s[n], 0, 0, 0);
        }
    __builtin_amdgcn_s_setprio(0);

    if (diag) {
        #pragma unroll
        for (int n = 0; n < 4; ++n)
            #pragma unroll
            for (int r = 0; r < 4; ++r)
                if (n * 16 + lg * 4 + r > qloc) s[n][r] = -3e38f;
    }

    float tmax = s[0][0];
    #pragma unroll
    for (int n = 0; n < 4; ++n)
        #pragma unroll
        for (int r = 0; r < 4; ++r) tmax = fmaxf(tmax, s[n][r]);
    tmax = fmaxf(tmax, __shfl_xor(tmax, 16));
    tmax = fmaxf(tmax, __shfl_xor(tmax, 32));

    // T13 defer-max: rescale only when some lane's tile-max exceeds the stale
    // running max by >8 (log2 units). Wave-uniform branch; P bounded by 2^8.
    if (__any(tmax > mrow + 8.f)) {
        const float mnew = fmaxf(mrow, tmax);
        const float scl = __builtin_amdgcn_exp2f(mrow - mnew);
        mrow = mnew;
        srow *= scl;
        #pragma unroll
        for (int nd = 0; nd < 8; ++nd)
            #pragma unroll
            for (int r = 0; r < 4; ++r) o[nd][r] *= scl;
    }

    float rs = 0.f;
    #pragma unroll
    for (int n = 0; n < 4; ++n)
        #pragma unroll
        for (int r = 0; r < 4; ++r) {
            const float p = __builtin_amdgcn_exp2f(s[n][r] - mrow);
            s[n][r] = p;
            rs += p;
        }
    rs += __shfl_xor(rs, 16);
    rs += __shfl_xor(rs, 32);
    srow += rs;

    #pragma unroll
    for (int n = 0; n < 4; ++n)
        #pragma unroll
        for (int rp = 0; rp < 2; ++rp) {
            const int col = n * 16 + lg * 4 + rp * 2;
            bf16x2 pk;
            pk.x = (__bf16)s[n][rp * 2];
            pk.y = (__bf16)s[n][rp * 2 + 1];
            *reinterpret_cast<bf16x2*>(
                PlB + ll * 128 + (((col >> 3) ^ (ll & 7)) << 4) + (col & 7) * 2) = pk;
        }

    __builtin_amdgcn_s_setprio(1);
    #pragma unroll
    for (int kk = 0; kk < 2; ++kk) {
        bf16x8 pf = *reinterpret_cast<const bf16x8*>(
            PlB + ll * 128 + (((kk * 4 + lg) ^ (ll & 7)) << 4));
        #pragma unroll
        for (int nd = 0; nd < 8; ++nd) {
            const int row = nd * 16 + ll;
            bf16x8 vf = *reinterpret_cast<const bf16x8*>(
                VlB + row * 128 + (((kk * 4 + lg) ^ (ll & 7)) << 4));
            o[nd] = __builtin_amdgcn_mfma_f32_16x16x32_bf16(vf, pf, o[nd], 0, 0, 0);
        }
    }
    __builtin_amdgcn_s_setprio(0);
}

// ---------- causal GQA flash attention: paired Q-tiles, gl_lds dbuf staging ----------
// grid 512 = 16 (qp) x 32 (hb). Block handles q-blocks lo=qp and hi=31-qp:
// lo's key range is a prefix of hi's -> shared K/V staging; per-block MFMA
// work = 33 tile-units, exactly uniform. Double-buffered K/V via
// global_load_lds (pre-swizzled source, linear dest), counted vmcnt(8).
__global__ __launch_bounds__(256)
void attn_kernel(const __bf16* __restrict__ qT, const __bf16* __restrict__ kT,
                 const __bf16* __restrict__ vT, __bf16* __restrict__ attnb) {
    const int bx = blockIdx.x;
    const int qp = bx >> 5;
    const int hb = bx & 31;
    const int h = hb >> 1, b = hb & 1;
    const int kv = h >> 3;
    const int lo = qp, hi = 31 - qp;
    const int tid = threadIdx.x, wave = tid >> 6, lane = tid & 63, lg = lane >> 4, ll = lane & 15;
    const int qloc = wave * 16 + ll;   // q-row within the 64-row q-block

    __shared__ __align__(16) char smem[73728];   // 2 x (K 16K + V 16K) + P 8K
    lds_bf16* ldsE = (lds_bf16*)smem;

    const __bf16* kbase = kT + (size_t)((b * 2 + kv) * 2048) * 128;
    const __bf16* vbase = vT + (size_t)((b * 2 + kv) * 128) * 2048;

    bf16x8 qfL[4], qfH[4];
    {
        const __bf16* q0 = qT + ((size_t)((b * 16 + h) * 2048) + lo * 64 + wave * 16 + ll) * 128;
        const __bf16* q1 = qT + ((size_t)((b * 16 + h) * 2048) + hi * 64 + wave * 16 + ll) * 128;
        #pragma unroll
        for (int kk = 0; kk < 4; ++kk) {
            qfL[kk] = *reinterpret_cast<const bf16x8*>(q0 + kk * 32 + lg * 8);
            qfH[kk] = *reinterpret_cast<const bf16x8*>(q1 + kk * 32 + lg * 8);
        }
    }

    f32x4 oL[8], oH[8];
    #pragma unroll
    for (int nd = 0; nd < 8; ++nd) { oL[nd] = f32x4{0.f,0.f,0.f,0.f}; oH[nd] = f32x4{0.f,0.f,0.f,0.f}; }
    float mL = -3e38f, sL = 0.f, mH = -3e38f, sH = 0.f;

    const int ntiles = hi + 1;

    #define STAGE_KV(j0, buf)                                                              \
        do {                                                                               \
            lds_bf16* kl = ldsE + (buf) * 16384;                                           \
            lds_bf16* vl = ldsE + (buf) * 16384 + 8192;                                    \
            _Pragma("unroll")                                                              \
            for (int i = 0; i < 4; ++i) {                                                  \
                const int li = i * 256 + tid;                                              \
                const int key = li >> 4, c = li & 15;                                      \
                const __bf16* src = kbase + (size_t)((j0) + key) * 128 + ((c ^ (key & 7)) * 8); \
                __builtin_amdgcn_global_load_lds((gl_bf16*)src, kl + i * 2048 + wave * 512, 16, 0, 0); \
            }                                                                              \
            _Pragma("unroll")                                                              \
            for (int i = 0; i < 4; ++i) {                                                  \
                const int li = i * 256 + tid;                                              \
                const int dd = li >> 3, cv = li & 7;                                       \
                const __bf16* src = vbase + (size_t)dd * 2048 + (j0) + ((cv ^ (dd & 7)) * 8); \
                __builtin_amdgcn_global_load_lds((gl_bf16*)src, vl + i * 2048 + wave * 512, 16, 0, 0); \
            }                                                                              \
        } while (0)

    STAGE_KV(0, 0);
    char* PlB = smem + 65536 + wave * 2048;

    for (int t = 0; t < ntiles; ++t) {
        const int tn = (t + 1 < ntiles) ? t + 1 : t;   // clamp keeps vmcnt uniform
        STAGE_KV(tn * 64, (t + 1) & 1);
        asm volatile("s_waitcnt vmcnt(8)" ::: "memory");
        __builtin_amdgcn_s_barrier();
        asm volatile("" ::: "memory");

        const char* KlB = smem + (t & 1) * 32768;
        const char* VlB = smem + (t & 1) * 32768 + 16384;

        // HI group (always active)
        attn_step(KlB, VlB, PlB, qfH, oH, mH, sH, t == hi, lg, ll, qloc);
        // LO group (prefix of HI's key range)
        if (t <= lo)
            attn_step(KlB, VlB, PlB, qfL, oL, mL, sL, t == lo, lg, ll, qloc);

        asm volatile("" ::: "memory");
        __builtin_amdgcn_s_barrier();
        asm volatile("" ::: "memory");
    }

    // epilogue: O^T layout -> lane owns q, 4 consecutive d per store
    const float invH = __builtin_amdgcn_rcpf(sH);
    const float invL = __builtin_amdgcn_rcpf(sL);
    const int qHrow = hi * 64 + wave * 16 + ll;
    const int qLrow = lo * 64 + wave * 16 + ll;
    #pragma unroll
    for (int nd = 0; nd < 8; ++nd) {
        bf16x4 aH, aL;
        #pragma unroll
        for (int r = 0; r < 4; ++r) {
            aH[r] = (__bf16)(oH[nd][r] * invH);
            aL[r] = (__bf16)(oL[nd][r] * invL);
        }
        const size_t cb = h * 128 + nd * 16 + lg * 4;
        *reinterpret_cast<bf16x4*>(&attnb[((size_t)(b * 2048) + qHrow) * 2048 + cb]) = aH;
        *reinterpret_cast<bf16x4*>(&attnb[((size_t)(b * 2048) + qLrow) * 2048 + cb]) = aL;
    }
    #undef STAGE_KV
}

// ---------- host launch ----------
extern "C" void kernel_launch(void* const* d_in, const int* in_sizes, int n_in,
                              void* d_out, int out_size, void* d_ws, size_t ws_size,
                              hipStream_t stream) {
    const float* x    = (const float*)d_in[0];
    const float* cosb = (const float*)d_in[1];
    const float* sinb = (const float*)d_in[2];
    const float* wq   = (const float*)d_in[3];
    const float* bq   = (const float*)d_in[4];
    const float* wk   = (const float*)d_in[5];
    const float* bk   = (const float*)d_in[6];
    const float* wv   = (const float*)d_in[7];
    const float* bv   = (const float*)d_in[8];
    const float* wo   = (const float*)d_in[9];
    float* out = (float*)d_out;

    char* ws = (char*)d_ws;
    __bf16* xb    = (__bf16*)(ws);                         // 16,777,216  (later reused as attnb)
    __bf16* wb    = (__bf16*)(ws + 16777216);              // 10,485,760  (wq|wk|wv rows, 2560x2048)
    __bf16* wob   = (__bf16*)(ws + 27262976);              //  8,388,608
    float*  biasc = (float*) (ws + 35651584);              //     16,384 (2560 used)
    __bf16* qTp   = (__bf16*)(ws + 77611008);              // 16,777,216
    __bf16* kTp   = (__bf16*)(ws + 94388224);              //  2,097,152
    __bf16* vTp   = (__bf16*)(ws + 96485376);              //  2,097,152

    // 1) convert all fp32 inputs to bf16 (wq/wk pair-interleave-permuted)
    cvt_all<<<17408, 256, 0, stream>>>(
        x,  xb,
        wq, wb,
        wk, wb + 4194304,
        wv, wb + 4718592,
        wo, wob);
    concat_bias<<<10, 256, 0, stream>>>(bq, bk, bv, biasc);

    // 2) fused QKV GEMM + bias + RoPE + layout  [256 wg = full fill, 512 thr]
    gemm_qkv_rope<<<256, 512, 0, stream>>>(xb, wb, biasc, cosb, sinb, qTp, kTp, vTp);

    // 3) flash attention -> attnb (reuses xb region, bf16 (B,L,H*D))
    attn_kernel<<<512, 256, 0, stream>>>(qTp, kTp, vTp, xb);

    // 4) output GEMM: 256x128 tiles, grid 256 (perfect fill), pipelined
    gemm_out<<<256, 512, 0, stream>>>(xb, wob, out);
}

// Round 21
// 175.599 us; speedup vs baseline: 1.1193x; 1.0148x over previous
//
#include <hip/hip_runtime.h>
#include <hip/hip_bf16.h>
#include <cstdint>

// ---------- types ----------
typedef __bf16 bf16x8 __attribute__((ext_vector_type(8)));
typedef __bf16 bf16x4 __attribute__((ext_vector_type(4)));
typedef __bf16 bf16x2 __attribute__((ext_vector_type(2)));
typedef float  f32x4  __attribute__((ext_vector_type(4)));
typedef __attribute__((address_space(3))) __bf16 lds_bf16;
typedef __attribute__((address_space(1))) const __bf16 gl_bf16;

// ---------- merged fp32 -> bf16 convert + bias concat (one launch) ----------
// wq/wk segments are written ROW-PERMUTED: within each 128-row head,
// original row d -> ((d&63)<<1) + (d>>6)  (pair-interleave: RoPE partner
// d^64 becomes the adjacent row). Inverse applied in the GEMM epilogue.
// Blocks 17408..17417 handle the bias concat (same permutation for Q/K parts).
__global__ void cvt_all(const float* __restrict__ s0, __bf16* __restrict__ d0,
                        const float* __restrict__ s1, __bf16* __restrict__ d1,
                        const float* __restrict__ s2, __bf16* __restrict__ d2,
                        const float* __restrict__ s3, __bf16* __restrict__ d3,
                        const float* __restrict__ s4, __bf16* __restrict__ d4,
                        const float* __restrict__ bq, const float* __restrict__ bk,
                        const float* __restrict__ bv, float* __restrict__ biasd) {
    const int blk = blockIdx.x;
    if (blk >= 17408) {
        const int t = (blk - 17408) * 256 + threadIdx.x;
        if (t < 2048) {
            const int h = t >> 7, d = t & 127;
            biasd[(h << 7) + ((d & 63) << 1) + (d >> 6)] = bq[t];
        } else if (t < 2304) {
            const int u = t - 2048, kvh = u >> 7, d = u & 127;
            biasd[2048 + (kvh << 7) + ((d & 63) << 1) + (d >> 6)] = bk[u];
        } else if (t < 2560) {
            biasd[t] = bv[t - 2304];
        }
        return;
    }
    const float* s; __bf16* d; int base; bool perm = false;
    if (blk < 8192)       { s = s0; d = d0; base = blk; }
    else if (blk < 12288) { s = s1; d = d1; base = blk - 8192;  perm = true; }
    else if (blk < 12800) { s = s2; d = d2; base = blk - 12288; perm = true; }
    else if (blk < 13312) { s = s3; d = d3; base = blk - 12800; }
    else                  { s = s4; d = d4; base = blk - 13312; }
    const int i = (base * 256 + threadIdx.x) * 4;
    float4 v = *reinterpret_cast<const float4*>(s + i);
    bf16x4 o;
    o.x = (__bf16)v.x; o.y = (__bf16)v.y; o.z = (__bf16)v.z; o.w = (__bf16)v.w;
    int iout = i;
    if (perm) {
        const int row = base >> 1;                 // 1024 elems = half row of 2048
        const int h = row >> 7, dd = row & 127;
        const int pr = (h << 7) + ((dd & 63) << 1) + (dd >> 6);
        iout = pr * 2048 + (base & 1) * 1024 + threadIdx.x * 4;
    }
    *reinterpret_cast<bf16x4*>(d + iout) = o;
}

// ---------- stage one 128x64 half-tile: 2 global_load_lds per thread ----------
__device__ __forceinline__ void stage_half(const __bf16* __restrict__ gbase, int K, int k0,
                                           lds_bf16* lbase, int tid) {
    const int cc = (tid & 7) ^ ((tid >> 3) & 7);
    const __bf16* s0 = gbase + (size_t)(tid >> 3) * K + k0 + cc * 8;
    __builtin_amdgcn_global_load_lds((gl_bf16*)s0, lbase + (tid >> 6) * 512, 16, 0, 0);
    const __bf16* s1 = gbase + (size_t)(64 + (tid >> 3)) * K + k0 + cc * 8;
    __builtin_amdgcn_global_load_lds((gl_bf16*)s1, lbase + 4096 + (tid >> 6) * 512, 16, 0, 0);
}

// ---------- stage a 320x64 B-tile: 5 stripes of 64 rows ----------
__device__ __forceinline__ void stage_B5(const __bf16* __restrict__ gbase, int K, int k0,
                                         lds_bf16* lbase, int tid) {
    const int cc = (tid & 7) ^ ((tid >> 3) & 7);
    #pragma unroll
    for (int s = 0; s < 5; ++s) {
        const __bf16* src = gbase + (size_t)(s * 64 + (tid >> 3)) * K + k0 + cc * 8;
        __builtin_amdgcn_global_load_lds((gl_bf16*)src, lbase + s * 4096 + (tid >> 6) * 512, 16, 0, 0);
    }
}

// ---------- out-proj GEMM: 256x128 tile, grid 256 (perfect fill) ----------
__global__ __launch_bounds__(512)
void gemm_out(const __bf16* __restrict__ A, const __bf16* __restrict__ B,
              float* __restrict__ C) {
    const int K = 2048, NT = 32;
    __shared__ __align__(16) char smem[98304];

    const int tid  = threadIdx.x;
    const int wave = tid >> 6, lane = tid & 63, lg = lane >> 4, ll = lane & 15;
    const int wr = wave >> 2, wc = wave & 3;

    const int orig = blockIdx.x;
    const int wg   = (orig & 7) * 32 + (orig >> 3);
    const int bm = wg >> 4, bn = wg & 15;

    const __bf16* Atile = A + (size_t)(bm * 256) * K;
    const __bf16* Btile = B + (size_t)(bn * 128) * K;

    lds_bf16* AsL = (lds_bf16*)smem;
    lds_bf16* BsL = (lds_bf16*)(smem + 65536);

    f32x4 acc[8][2];
    #pragma unroll
    for (int m = 0; m < 8; ++m)
        #pragma unroll
        for (int n = 0; n < 2; ++n)
            acc[m][n] = f32x4{0.f, 0.f, 0.f, 0.f};

    stage_half(Atile,                 K, 0, AsL,        tid);
    stage_half(Atile + (size_t)128*K, K, 0, AsL + 8192, tid);
    stage_half(Btile,                 K, 0, BsL,        tid);

    const char* smB = (const char*)smem;
    for (int t = 0; t < NT; ++t) {
        const int c   = t & 1;
        const int bfn = c ^ 1;
        const int k0n = ((t + 1 < NT) ? t + 1 : t) * 64;
        const char* AbB = smB + c * 32768 + wr * 16384;
        const char* BbB = smB + 65536 + c * 16384;
        bf16x8 af[8][2], bq[2][2];

        stage_half(Atile,                 K, k0n, AsL + bfn * 8192 * 2,        tid);
        stage_half(Atile + (size_t)128*K, K, k0n, AsL + bfn * 8192 * 2 + 8192, tid);
        asm volatile("s_waitcnt vmcnt(4)" ::: "memory");
        __builtin_amdgcn_s_barrier();
        asm volatile("" ::: "memory");
        #pragma unroll
        for (int kk = 0; kk < 2; ++kk) {
            #pragma unroll
            for (int mm = 0; mm < 8; ++mm)
                af[mm][kk] = *reinterpret_cast<const bf16x8*>(
                    AbB + (mm * 16 + ll) * 128 + (((kk * 4 + lg) ^ (ll & 7)) << 4));
            #pragma unroll
            for (int nn = 0; nn < 2; ++nn)
                bq[nn][kk] = *reinterpret_cast<const bf16x8*>(
                    BbB + (wc * 32 + nn * 16 + ll) * 128 + (((kk * 4 + lg) ^ (ll & 7)) << 4));
        }
        __builtin_amdgcn_s_setprio(1);
        #pragma unroll
        for (int kk = 0; kk < 2; ++kk)
            #pragma unroll
            for (int mm = 0; mm < 4; ++mm)
                #pragma unroll
                for (int nn = 0; nn < 2; ++nn)
                    acc[mm][nn] = __builtin_amdgcn_mfma_f32_16x16x32_bf16(af[mm][kk], bq[nn][kk], acc[mm][nn], 0, 0, 0);
        __builtin_amdgcn_s_setprio(0);
        asm volatile("" ::: "memory");
        __builtin_amdgcn_s_barrier();
        asm volatile("" ::: "memory");

        stage_half(Btile, K, k0n, BsL + bfn * 8192, tid);
        __builtin_amdgcn_s_setprio(1);
        #pragma unroll
        for (int kk = 0; kk < 2; ++kk)
            #pragma unroll
            for (int mm = 0; mm < 4; ++mm)
                #pragma unroll
                for (int nn = 0; nn < 2; ++nn)
                    acc[4 + mm][nn] = __builtin_amdgcn_mfma_f32_16x16x32_bf16(af[4 + mm][kk], bq[nn][kk], acc[4 + mm][nn], 0, 0, 0);
        __builtin_amdgcn_s_setprio(0);
        asm volatile("" ::: "memory");
        __builtin_amdgcn_s_barrier();
        asm volatile("" ::: "memory");
    }

    asm volatile("s_waitcnt vmcnt(0)" ::: "memory");

    #pragma unroll
    for (int m = 0; m < 8; ++m)
        #pragma unroll
        for (int n = 0; n < 2; ++n) {
            const int col = bn * 128 + wc * 32 + n * 16 + ll;
            #pragma unroll
            for (int r = 0; r < 4; ++r) {
                const int rowg = bm * 256 + wr * 128 + m * 16 + lg * 4 + r;
                C[(size_t)rowg * 2048 + col] = acc[m][n][r];
            }
        }
}

// ---------- QKV GEMM 128x320, BK=64, grid 256 (full fill), fused bias+RoPE ----------
__global__ __launch_bounds__(512)
void gemm_qkv_rope(const __bf16* __restrict__ A, const __bf16* __restrict__ B,
                   const float* __restrict__ bias, const float* __restrict__ cosb,
                   const float* __restrict__ sinb, __bf16* __restrict__ qT,
                   __bf16* __restrict__ kT, __bf16* __restrict__ vT) {
    const int K = 2048, NT = 32;
    __shared__ __align__(16) char smem[114688];   // A: 2x16KB [0,32K); B: 2x40KB [32K,112K)

    const int tid  = threadIdx.x;
    const int wave = tid >> 6, lane = tid & 63, lg = lane >> 4, ll = lane & 15;
    const int wr = wave >> 2, wc = wave & 3;       // 2M x 4N; per-wave 64 x 80

    const int orig = blockIdx.x;                   // 256 wg, %8 == 0
    const int wg   = (orig & 7) * 32 + (orig >> 3);
    const int bm = wg >> 3, bn = wg & 7;           // 32 x 8

    const __bf16* Atile = A + (size_t)(bm * 128) * K;
    const __bf16* Btile = B + (size_t)(bn * 320) * K;

    lds_bf16* AsL = (lds_bf16*)smem;               // per buf 8192 elems
    lds_bf16* BsL = (lds_bf16*)(smem + 32768);     // per buf 20480 elems

    f32x4 acc[4][5];
    #pragma unroll
    for (int m = 0; m < 4; ++m)
        #pragma unroll
        for (int n = 0; n < 5; ++n)
            acc[m][n] = f32x4{0.f, 0.f, 0.f, 0.f};

    // prologue: tile 0 -> buf 0
    stage_half(Atile, K, 0, AsL, tid);
    stage_B5 (Btile, K, 0, BsL, tid);
    asm volatile("s_waitcnt vmcnt(0)" ::: "memory");
    __syncthreads();

    const char* smB = (const char*)smem;
    for (int t = 0; t < NT; ++t) {
        const int c   = t & 1;
        const int bfn = c ^ 1;
        const int k0n = ((t + 1 < NT) ? t + 1 : t) * 64;   // clamp keeps counts uniform

        // issue next tile's 7 loads
        stage_half(Atile, K, k0n, AsL + bfn * 8192,  tid);
        stage_B5 (Btile, K, k0n, BsL + bfn * 20480, tid);
        asm volatile("s_waitcnt vmcnt(7)" ::: "memory");   // retire THIS tile's 7
        __builtin_amdgcn_s_barrier();
        asm volatile("" ::: "memory");

        const char* AbB = smB + c * 16384 + wr * 8192;
        const char* BbB = smB + 32768 + c * 40960;
        bf16x8 af[4][2], bq[5][2];
        #pragma unroll
        for (int kk = 0; kk < 2; ++kk) {
            #pragma unroll
            for (int mm = 0; mm < 4; ++mm)
                af[mm][kk] = *reinterpret_cast<const bf16x8*>(
                    AbB + (mm * 16 + ll) * 128 + (((kk * 4 + lg) ^ (ll & 7)) << 4));
            #pragma unroll
            for (int nn = 0; nn < 5; ++nn)
                bq[nn][kk] = *reinterpret_cast<const bf16x8*>(
                    BbB + (wc * 80 + nn * 16 + ll) * 128 + (((kk * 4 + lg) ^ (ll & 7)) << 4));
        }
        __builtin_amdgcn_s_setprio(1);
        #pragma unroll
        for (int kk = 0; kk < 2; ++kk)
            #pragma unroll
            for (int mm = 0; mm < 4; ++mm)
                #pragma unroll
                for (int nn = 0; nn < 5; ++nn)
                    acc[mm][nn] = __builtin_amdgcn_mfma_f32_16x16x32_bf16(af[mm][kk], bq[nn][kk], acc[mm][nn], 0, 0, 0);
        __builtin_amdgcn_s_setprio(0);
        asm volatile("" ::: "memory");
        __builtin_amdgcn_s_barrier();
        asm volatile("" ::: "memory");
    }

    asm volatile("s_waitcnt vmcnt(0)" ::: "memory");   // drain clamped tail prefetch

    // ---- epilogue: per-section (uniform per 16-lane group) ----
    const float qscale = 0.08838834764831845f * 1.4426950408889634f;
    #pragma unroll
    for (int n = 0; n < 5; ++n) {
        const int scol = bn * 320 + wc * 80 + n * 16;   // 16-aligned section base
        const int gcol = scol + ll;
        if (scol >= 2304) {
            // V: bias only, transposed store (b, kv, d, l)
            const int kvh = (gcol - 2304) >> 7, d = (gcol - 2304) & 127;
            const float bv = bias[gcol];
            #pragma unroll
            for (int m = 0; m < 4; ++m) {
                const int rbase = bm * 128 + wr * 64 + m * 16 + lg * 4;
                const int b = rbase >> 11, l0 = rbase & 2047;
                bf16x4 o4;
                #pragma unroll
                for (int r = 0; r < 4; ++r) o4[r] = (__bf16)(acc[m][n][r] + bv);
                *reinterpret_cast<bf16x4*>(&vT[((size_t)(b * 2 + kvh) * 128 + d) * 2048 + l0]) = o4;
            }
        } else {
            const bool isQ = (scol < 2048);
            const float qsc = isQ ? qscale : 1.0f;
            const int p = gcol & 127;                       // pair-interleaved index
            const int d_out = (p >> 1) + ((p & 1) << 6);    // original d
            const float sgn = (p & 1) ? 1.f : -1.f;
            const float bv = bias[gcol];
            #pragma unroll
            for (int m = 0; m < 4; ++m) {
                #pragma unroll
                for (int r = 0; r < 4; ++r) {
                    const float self = acc[m][n][r] + bv;
                    const float part = __shfl_xor(self, 1);
                    const int rowg = bm * 128 + wr * 64 + m * 16 + lg * 4 + r;
                    const int b = rowg >> 11, l = rowg & 2047;
                    const float cc = cosb[l * 128 + d_out], ss = sinb[l * 128 + d_out];
                    const float val = (self * cc + sgn * part * ss) * qsc;
                    if (isQ) {
                        const int h = gcol >> 7;
                        qT[(((size_t)(b * 16 + h)) * 2048 + l) * 128 + d_out] = (__bf16)val;
                    } else {
                        const int kvh = (gcol - 2048) >> 7;
                        kT[(((size_t)(b * 2 + kvh)) * 2048 + l) * 128 + d_out] = (__bf16)val;
                    }
                }
            }
        }
    }
}

// ---------- attn: one Q-group step with wave-uniform defer-max (T13) ----------
__device__ __forceinline__ void attn_step(const char* KlB, const char* VlB, char* PlB,
                                          const bf16x8* qf, f32x4* o, float& mrow, float& srow,
                                          bool diag, int lg, int ll, int qloc) {
    f32x4 s[4];
    #pragma unroll
    for (int n = 0; n < 4; ++n) s[n] = f32x4{0.f, 0.f, 0.f, 0.f};
    __builtin_amdgcn_s_setprio(1);
    #pragma unroll
    for (int kk = 0; kk < 4; ++kk)
        #pragma unroll
        for (int n = 0; n < 4; ++n) {
            const int row = n * 16 + ll;
            bf16x8 kf = *reinterpret_cast<const bf16x8*>(
                KlB + row * 256 + (((kk * 4 + lg) ^ (ll & 7)) << 4));
            s[n] = __builtin_amdgcn_mfma_f32_16x16x32_bf16(kf, qf[kk], s[n], 0, 0, 0);
        }
    __builtin_amdgcn_s_setprio(0);

    if (diag) {
        #pragma unroll
        for (int n = 0; n < 4; ++n)
            #pragma unroll
            for (int r = 0; r < 4; ++r)
                if (n * 16 + lg * 4 + r > qloc) s[n][r] = -3e38f;
    }

    float tmax = s[0][0];
    #pragma unroll
    for (int n = 0; n < 4; ++n)
        #pragma unroll
        for (int r = 0; r < 4; ++r) tmax = fmaxf(tmax, s[n][r]);
    tmax = fmaxf(tmax, __shfl_xor(tmax, 16));
    tmax = fmaxf(tmax, __shfl_xor(tmax, 32));

    // T13 defer-max: rescale only when some lane's tile-max exceeds the stale
    // running max by >8 (log2 units). Wave-uniform branch; P bounded by 2^8.
    if (__any(tmax > mrow + 8.f)) {
        const float mnew = fmaxf(mrow, tmax);
        const float scl = __builtin_amdgcn_exp2f(mrow - mnew);
        mrow = mnew;
        srow *= scl;
        #pragma unroll
        for (int nd = 0; nd < 8; ++nd)
            #pragma unroll
            for (int r = 0; r < 4; ++r) o[nd][r] *= scl;
    }

    float rs = 0.f;
    #pragma unroll
    for (int n = 0; n < 4; ++n)
        #pragma unroll
        for (int r = 0; r < 4; ++r) {
            const float p = __builtin_amdgcn_exp2f(s[n][r] - mrow);
            s[n][r] = p;
            rs += p;
        }
    rs += __shfl_xor(rs, 16);
    rs += __shfl_xor(rs, 32);
    srow += rs;

    #pragma unroll
    for (int n = 0; n < 4; ++n)
        #pragma unroll
        for (int rp = 0; rp < 2; ++rp) {
            const int col = n * 16 + lg * 4 + rp * 2;
            bf16x2 pk;
            pk.x = (__bf16)s[n][rp * 2];
            pk.y = (__bf16)s[n][rp * 2 + 1];
            *reinterpret_cast<bf16x2*>(
                PlB + ll * 128 + (((col >> 3) ^ (ll & 7)) << 4) + (col & 7) * 2) = pk;
        }

    __builtin_amdgcn_s_setprio(1);
    #pragma unroll
    for (int kk = 0; kk < 2; ++kk) {
        bf16x8 pf = *reinterpret_cast<const bf16x8*>(
            PlB + ll * 128 + (((kk * 4 + lg) ^ (ll & 7)) << 4));
        #pragma unroll
        for (int nd = 0; nd < 8; ++nd) {
            const int row = nd * 16 + ll;
            bf16x8 vf = *reinterpret_cast<const bf16x8*>(
                VlB + row * 128 + (((kk * 4 + lg) ^ (ll & 7)) << 4));
            o[nd] = __builtin_amdgcn_mfma_f32_16x16x32_bf16(vf, pf, o[nd], 0, 0, 0);
        }
    }
    __builtin_amdgcn_s_setprio(0);
}

// ---------- causal GQA flash attention: paired Q-tiles, gl_lds dbuf staging ----------
// grid 512 = 16 (qp) x 32 (hb). Block handles q-blocks lo=qp and hi=31-qp:
// lo's key range is a prefix of hi's -> shared K/V staging; per-block MFMA
// work = 33 tile-units, exactly uniform. Double-buffered K/V via
// global_load_lds (pre-swizzled source, linear dest), counted vmcnt(8).
__global__ __launch_bounds__(256)
void attn_kernel(const __bf16* __restrict__ qT, const __bf16* __restrict__ kT,
                 const __bf16* __restrict__ vT, __bf16* __restrict__ attnb) {
    const int bx = blockIdx.x;
    const int qp = bx >> 5;
    const int hb = bx & 31;
    const int h = hb >> 1, b = hb & 1;
    const int kv = h >> 3;
    const int lo = qp, hi = 31 - qp;
    const int tid = threadIdx.x, wave = tid >> 6, lane = tid & 63, lg = lane >> 4, ll = lane & 15;
    const int qloc = wave * 16 + ll;   // q-row within the 64-row q-block

    __shared__ __align__(16) char smem[73728];   // 2 x (K 16K + V 16K) + P 8K
    lds_bf16* ldsE = (lds_bf16*)smem;

    const __bf16* kbase = kT + (size_t)((b * 2 + kv) * 2048) * 128;
    const __bf16* vbase = vT + (size_t)((b * 2 + kv) * 128) * 2048;

    bf16x8 qfL[4], qfH[4];
    {
        const __bf16* q0 = qT + ((size_t)((b * 16 + h) * 2048) + lo * 64 + wave * 16 + ll) * 128;
        const __bf16* q1 = qT + ((size_t)((b * 16 + h) * 2048) + hi * 64 + wave * 16 + ll) * 128;
        #pragma unroll
        for (int kk = 0; kk < 4; ++kk) {
            qfL[kk] = *reinterpret_cast<const bf16x8*>(q0 + kk * 32 + lg * 8);
            qfH[kk] = *reinterpret_cast<const bf16x8*>(q1 + kk * 32 + lg * 8);
        }
    }

    f32x4 oL[8], oH[8];
    #pragma unroll
    for (int nd = 0; nd < 8; ++nd) { oL[nd] = f32x4{0.f,0.f,0.f,0.f}; oH[nd] = f32x4{0.f,0.f,0.f,0.f}; }
    float mL = -3e38f, sL = 0.f, mH = -3e38f, sH = 0.f;

    const int ntiles = hi + 1;

    #define STAGE_KV(j0, buf)                                                              \
        do {                                                                               \
            lds_bf16* kl = ldsE + (buf) * 16384;                                           \
            lds_bf16* vl = ldsE + (buf) * 16384 + 8192;                                    \
            _Pragma("unroll")                                                              \
            for (int i = 0; i < 4; ++i) {                                                  \
                const int li = i * 256 + tid;                                              \
                const int key = li >> 4, c = li & 15;                                      \
                const __bf16* src = kbase + (size_t)((j0) + key) * 128 + ((c ^ (key & 7)) * 8); \
                __builtin_amdgcn_global_load_lds((gl_bf16*)src, kl + i * 2048 + wave * 512, 16, 0, 0); \
            }                                                                              \
            _Pragma("unroll")                                                              \
            for (int i = 0; i < 4; ++i) {                                                  \
                const int li = i * 256 + tid;                                              \
                const int dd = li >> 3, cv = li & 7;                                       \
                const __bf16* src = vbase + (size_t)dd * 2048 + (j0) + ((cv ^ (dd & 7)) * 8); \
                __builtin_amdgcn_global_load_lds((gl_bf16*)src, vl + i * 2048 + wave * 512, 16, 0, 0); \
            }                                                                              \
        } while (0)

    STAGE_KV(0, 0);
    char* PlB = smem + 65536 + wave * 2048;

    for (int t = 0; t < ntiles; ++t) {
        const int tn = (t + 1 < ntiles) ? t + 1 : t;   // clamp keeps vmcnt uniform
        STAGE_KV(tn * 64, (t + 1) & 1);
        asm volatile("s_waitcnt vmcnt(8)" ::: "memory");
        __builtin_amdgcn_s_barrier();
        asm volatile("" ::: "memory");

        const char* KlB = smem + (t & 1) * 32768;
        const char* VlB = smem + (t & 1) * 32768 + 16384;

        // HI group (always active)
        attn_step(KlB, VlB, PlB, qfH, oH, mH, sH, t == hi, lg, ll, qloc);
        // LO group (prefix of HI's key range)
        if (t <= lo)
            attn_step(KlB, VlB, PlB, qfL, oL, mL, sL, t == lo, lg, ll, qloc);

        asm volatile("" ::: "memory");
        __builtin_amdgcn_s_barrier();
        asm volatile("" ::: "memory");
    }

    // epilogue: O^T layout -> lane owns q, 4 consecutive d per store
    const float invH = __builtin_amdgcn_rcpf(sH);
    const float invL = __builtin_amdgcn_rcpf(sL);
    const int qHrow = hi * 64 + wave * 16 + ll;
    const int qLrow = lo * 64 + wave * 16 + ll;
    #pragma unroll
    for (int nd = 0; nd < 8; ++nd) {
        bf16x4 aH, aL;
        #pragma unroll
        for (int r = 0; r < 4; ++r) {
            aH[r] = (__bf16)(oH[nd][r] * invH);
            aL[r] = (__bf16)(oL[nd][r] * invL);
        }
        const size_t cb = h * 128 + nd * 16 + lg * 4;
        *reinterpret_cast<bf16x4*>(&attnb[((size_t)(b * 2048) + qHrow) * 2048 + cb]) = aH;
        *reinterpret_cast<bf16x4*>(&attnb[((size_t)(b * 2048) + qLrow) * 2048 + cb]) = aL;
    }
    #undef STAGE_KV
}

// ---------- host launch ----------
extern "C" void kernel_launch(void* const* d_in, const int* in_sizes, int n_in,
                              void* d_out, int out_size, void* d_ws, size_t ws_size,
                              hipStream_t stream) {
    const float* x    = (const float*)d_in[0];
    const float* cosb = (const float*)d_in[1];
    const float* sinb = (const float*)d_in[2];
    const float* wq   = (const float*)d_in[3];
    const float* bq   = (const float*)d_in[4];
    const float* wk   = (const float*)d_in[5];
    const float* bk   = (const float*)d_in[6];
    const float* wv   = (const float*)d_in[7];
    const float* bv   = (const float*)d_in[8];
    const float* wo   = (const float*)d_in[9];
    float* out = (float*)d_out;

    char* ws = (char*)d_ws;
    __bf16* xb    = (__bf16*)(ws);                         // 16,777,216  (later reused as attnb)
    __bf16* wb    = (__bf16*)(ws + 16777216);              // 10,485,760  (wq|wk|wv rows, 2560x2048)
    __bf16* wob   = (__bf16*)(ws + 27262976);              //  8,388,608
    float*  biasc = (float*) (ws + 35651584);              //     16,384 (2560 used)
    __bf16* qTp   = (__bf16*)(ws + 77611008);              // 16,777,216
    __bf16* kTp   = (__bf16*)(ws + 94388224);              //  2,097,152
    __bf16* vTp   = (__bf16*)(ws + 96485376);              //  2,097,152

    // 1) convert all fp32 inputs to bf16 + bias concat (single launch)
    cvt_all<<<17418, 256, 0, stream>>>(
        x,  xb,
        wq, wb,
        wk, wb + 4194304,
        wv, wb + 4718592,
        wo, wob,
        bq, bk, bv, biasc);

    // 2) fused QKV GEMM + bias + RoPE + layout  [256 wg = full fill, 512 thr]
    gemm_qkv_rope<<<256, 512, 0, stream>>>(xb, wb, biasc, cosb, sinb, qTp, kTp, vTp);

    // 3) flash attention -> attnb (reuses xb region, bf16 (B,L,H*D))
    attn_kernel<<<512, 256, 0, stream>>>(qTp, kTp, vTp, xb);

    // 4) output GEMM: 256x128 tiles, grid 256 (perfect fill), pipelined
    gemm_out<<<256, 512, 0, stream>>>(xb, wob, out);
}